// Round 1
// baseline (312.651 us; speedup 1.0000x reference)
//
#include <hip/hip_runtime.h>
#include <math.h>

// B=4096, C=64, D=256, EPS=1e-5
#define BB 4096
#define CC 64
#define DD 256
#define EPSV 1e-5f
#define NORMC 4096.00064f  // B + C*EPS

// ---------------- K1: partial class sums + counts ----------------
// grid 256 = 32 bchunks (128 rows) x 8 colchunks (32 cols), 256 threads
__global__ void k1_class_sums(const float* __restrict__ z, const int* __restrict__ y,
                              float* __restrict__ Sp, int* __restrict__ cntp) {
    int bc = blockIdx.x >> 3;   // 0..31
    int cc = blockIdx.x & 7;    // 0..7
    int b0 = bc * 128;
    int c0 = cc * 32;
    __shared__ float acc[64][33];
    __shared__ int ycache[128];
    __shared__ int cnt[64];
    int t = threadIdx.x;
    for (int i = t; i < 64 * 33; i += 256) ((float*)acc)[i] = 0.f;
    if (t < 64) cnt[t] = 0;
    if (t < 128) ycache[t] = y[b0 + t];
    __syncthreads();
    int rr = t >> 5;       // 0..7
    int col = t & 31;      // 0..31
    for (int step = 0; step < 16; ++step) {
        int r = step * 8 + rr;
        float v = z[(b0 + r) * DD + c0 + col];
        atomicAdd(&acc[ycache[r]][col], v);
    }
    if (cc == 0 && t < 128) atomicAdd(&cnt[ycache[t]], 1);
    __syncthreads();
    for (int i = t; i < 64 * 32; i += 256) {
        int c = i >> 5, cl = i & 31;
        Sp[(bc * 64 + c) * DD + c0 + cl] = acc[c][cl];
    }
    if (cc == 0 && t < 64) cntp[bc * 64 + t] = cnt[t];
}

// ---------------- K2: finalize mu, counts_f, logprior ----------------
// grid 64 (one class each), 256 threads (d)
__global__ void k2_finalize(const float* __restrict__ Sp, const int* __restrict__ cntp,
                            float* __restrict__ mu, float* __restrict__ counts_f,
                            float* __restrict__ logprior) {
    int c = blockIdx.x;
    int t = threadIdx.x;
    __shared__ float cf;
    __shared__ int csum[32];
    if (t < 32) csum[t] = cntp[t * 64 + c];
    __syncthreads();
    if (t == 0) {
        int n = 0;
        for (int i = 0; i < 32; ++i) n += csum[i];
        float cfv = (float)n + EPSV;
        cf = cfv;
        counts_f[c] = cfv;
        logprior[c] = logf(cfv) - logf(NORMC);
    }
    __syncthreads();
    float s = 0.f;
    for (int i = 0; i < 32; ++i) s += Sp[(i * 64 + c) * DD + t];
    mu[c * DD + t] = s / cf;
}

// ---------------- K3: Z^T Z split-K partials ----------------
// grid 256 = 16 splitK x 16 tiles (4x4 of 64x64), 256 threads
__global__ void k3_ztz(const float* __restrict__ z, float* __restrict__ Zp) {
    int ks = blockIdx.x >> 4;
    int tile = blockIdx.x & 15;
    int ti = tile >> 2, tj = tile & 3;
    __shared__ float Za[32][64];
    __shared__ float Zb[32][64];
    int t = threadIdx.x;
    int b0 = ks * 256;
    float accv[4][4];
#pragma unroll
    for (int i = 0; i < 4; ++i)
#pragma unroll
        for (int j = 0; j < 4; ++j) accv[i][j] = 0.f;
    int i0 = (t & 15) * 4, j0 = (t >> 4) * 4;
    for (int sub = 0; sub < 8; ++sub) {
        int r0 = b0 + sub * 32;
        for (int f = t; f < 512; f += 256) {
            int row = f >> 4, c4 = (f & 15) * 4;
            *(float4*)&Za[row][c4] = *(const float4*)&z[(r0 + row) * DD + ti * 64 + c4];
            *(float4*)&Zb[row][c4] = *(const float4*)&z[(r0 + row) * DD + tj * 64 + c4];
        }
        __syncthreads();
#pragma unroll 8
        for (int kk = 0; kk < 32; ++kk) {
            float4 a = *(float4*)&Za[kk][i0];
            float4 b = *(float4*)&Zb[kk][j0];
            float av[4] = {a.x, a.y, a.z, a.w};
            float bv[4] = {b.x, b.y, b.z, b.w};
#pragma unroll
            for (int ii = 0; ii < 4; ++ii)
#pragma unroll
                for (int jj = 0; jj < 4; ++jj) accv[ii][jj] += av[ii] * bv[jj];
        }
        __syncthreads();
    }
    float* outp = Zp + ks * 65536;
#pragma unroll
    for (int ii = 0; ii < 4; ++ii) {
        int d = ti * 64 + i0 + ii;
        float4 v = make_float4(accv[ii][0], accv[ii][1], accv[ii][2], accv[ii][3]);
        *(float4*)&outp[d * DD + tj * 64 + j0] = v;
    }
}

// ---------------- K3b: assemble A = (ZtZ - sum_c w_c mu mu^T)/NORMC + eps I ----------------
// grid 256 (row d), 256 threads (col e); also row abs sums for Gershgorin
__global__ void k3b_assemble(const float* __restrict__ Zp, const float* __restrict__ mu,
                             const float* __restrict__ counts_f,
                             float* __restrict__ A, float* __restrict__ rowsum) {
    int d = blockIdx.x, e = threadIdx.x;
    __shared__ float wmu[64];
    __shared__ float red[4];
    if (e < 64) wmu[e] = (counts_f[e] + EPSV) * mu[e * DD + d];
    __syncthreads();
    float s = 0.f;
    for (int k = 0; k < 16; ++k) s += Zp[k * 65536 + d * DD + e];
    float corr = 0.f;
    for (int c = 0; c < 64; ++c) corr += wmu[c] * mu[c * DD + e];
    float val = (s - corr) * (1.0f / NORMC);
    if (d == e) val += EPSV;
    A[d * DD + e] = val;
    float v = fabsf(val);
    for (int off = 32; off > 0; off >>= 1) v += __shfl_down(v, off, 64);
    if ((e & 63) == 0) red[e >> 6] = v;
    __syncthreads();
    if (e == 0) rowsum[d] = red[0] + red[1] + red[2] + red[3];
}

// ---------------- K4: X0 = (1/max_rowsum) * I ----------------
// grid 64 (4 rows each), 256 threads
__global__ void k4_init(const float* __restrict__ rowsum, float* __restrict__ X) {
    __shared__ float red[256];
    int t = threadIdx.x;
    red[t] = rowsum[t];
    __syncthreads();
    for (int off = 128; off > 0; off >>= 1) {
        if (t < off) red[t] = fmaxf(red[t], red[t + off]);
        __syncthreads();
    }
    float alpha = 1.0f / red[0];
    int r0 = blockIdx.x * 4;
#pragma unroll
    for (int r = 0; r < 4; ++r)
        X[(r0 + r) * DD + t] = ((r0 + r) == t) ? alpha : 0.f;
}

// ---------------- K5: one Newton-Schulz iteration  Xd = 2*Xs - Xs*A*Xs ----------------
// grid 64 (4 rows each), 256 threads
__global__ void k5_ns(const float* __restrict__ A, const float* __restrict__ Xs,
                      float* __restrict__ Xd) {
    __shared__ float Xl[4][256];
    __shared__ float Rl[4][256];
    int t = threadIdx.x;
    int r0 = blockIdx.x * 4;
#pragma unroll
    for (int r = 0; r < 4; ++r) Xl[r][t] = Xs[(r0 + r) * DD + t];
    __syncthreads();
    float acc0 = 0.f, acc1 = 0.f, acc2 = 0.f, acc3 = 0.f;
    for (int k = 0; k < 256; ++k) {
        float a = A[k * DD + t];
        acc0 += Xl[0][k] * a; acc1 += Xl[1][k] * a;
        acc2 += Xl[2][k] * a; acc3 += Xl[3][k] * a;
    }
    Rl[0][t] = acc0; Rl[1][t] = acc1; Rl[2][t] = acc2; Rl[3][t] = acc3;
    __syncthreads();
    float o0 = 2.f * Xl[0][t], o1 = 2.f * Xl[1][t];
    float o2 = 2.f * Xl[2][t], o3 = 2.f * Xl[3][t];
    for (int k = 0; k < 256; ++k) {
        float xv = Xs[k * DD + t];
        o0 -= Rl[0][k] * xv; o1 -= Rl[1][k] * xv;
        o2 -= Rl[2][k] * xv; o3 -= Rl[3][k] * xv;
    }
    Xd[(r0 + 0) * DD + t] = o0;
    Xd[(r0 + 1) * DD + t] = o1;
    Xd[(r0 + 2) * DD + t] = o2;
    Xd[(r0 + 3) * DD + t] = o3;
}

// ---------------- K6: t_c = mu_c^T P mu_c ----------------
// grid 64 (one class), 256 threads
__global__ void k6_tc(const float* __restrict__ P, const float* __restrict__ mu,
                      float* __restrict__ tvec) {
    int c = blockIdx.x, t = threadIdx.x;
    __shared__ float mrow[256];
    __shared__ float red[4];
    mrow[t] = mu[c * DD + t];
    __syncthreads();
    float w = 0.f;
    for (int k = 0; k < 256; ++k) w += mrow[k] * P[k * DD + t];
    float v = w * mrow[t];
    for (int off = 32; off > 0; off >>= 1) v += __shfl_down(v, off, 64);
    if ((t & 63) == 0) red[t >> 6] = v;
    __syncthreads();
    if (t == 0) tvec[c] = red[0] + red[1] + red[2] + red[3];
}

// ---------------- K7: output ----------------
// out[b][c] = logprior_c + z_b^T P mu_c - 0.5*(z_b^T P z_b + t_c)
// grid 256 (16 rows each), 256 threads
__global__ void k7_out(const float* __restrict__ z, const float* __restrict__ P,
                       const float* __restrict__ mu, const float* __restrict__ logprior,
                       const float* __restrict__ tvec, float* __restrict__ out) {
    __shared__ float Zl[16][257];
    __shared__ float muL[32][257];
    __shared__ float qpart[16][4];
    __shared__ float qs[16];
    __shared__ float lp[64], tc[64];
    int t = threadIdx.x;
    int b0 = blockIdx.x * 16;
    if (t < 64) { lp[t] = logprior[t]; tc[t] = tvec[t]; }
    for (int i = t; i < 16 * 256; i += 256) {
        int r = i >> 8, k = i & 255;
        Zl[r][k] = z[(b0 + r) * DD + k];
    }
    __syncthreads();
    float zp[16];
#pragma unroll
    for (int r = 0; r < 16; ++r) zp[r] = 0.f;
    for (int k = 0; k < 256; ++k) {
        float p = P[k * DD + t];
#pragma unroll
        for (int r = 0; r < 16; ++r) zp[r] += Zl[r][k] * p;
    }
    int wid = t >> 6;
#pragma unroll
    for (int r = 0; r < 16; ++r) {
        float v = zp[r] * Zl[r][t];
        for (int off = 32; off > 0; off >>= 1) v += __shfl_down(v, off, 64);
        if ((t & 63) == 0) qpart[r][wid] = v;
    }
    __syncthreads();
    if (t < 16) qs[t] = qpart[t][0] + qpart[t][1] + qpart[t][2] + qpart[t][3];
    __syncthreads();
    // overwrite Zl with ZP (thread t holds column t)
#pragma unroll
    for (int r = 0; r < 16; ++r) Zl[r][t] = zp[r];
    __syncthreads();
    int rr = t >> 4, cg = t & 15;
    float res[4];
    for (int ch = 0; ch < 2; ++ch) {
        for (int i = t; i < 32 * 256; i += 256) {
            int c = i >> 8, k = i & 255;
            muL[c][k] = mu[(ch * 32 + c) * DD + k];
        }
        __syncthreads();
#pragma unroll
        for (int j = 0; j < 2; ++j) {
            int cl = cg + j * 16;
            float g = 0.f;
            for (int k = 0; k < 256; ++k) g += Zl[rr][k] * muL[cl][k];
            res[ch * 2 + j] = g;
        }
        __syncthreads();
    }
#pragma unroll
    for (int ch = 0; ch < 2; ++ch)
#pragma unroll
        for (int j = 0; j < 2; ++j) {
            int c = ch * 32 + j * 16 + cg;
            out[(b0 + rr) * CC + c] = lp[c] + res[ch * 2 + j] - 0.5f * (qs[rr] + tc[c]);
        }
}

extern "C" void kernel_launch(void* const* d_in, const int* in_sizes, int n_in,
                              void* d_out, int out_size, void* d_ws, size_t ws_size,
                              hipStream_t stream) {
    const float* z = (const float*)d_in[0];
    const int* y = (const int*)d_in[1];
    float* out = (float*)d_out;
    float* ws = (float*)d_ws;

    // workspace layout (floats)
    float* Sp       = ws;                  // 32*64*256 = 524288
    float* Zp       = ws + 524288;         // 16*65536  = 1048576
    float* A        = ws + 1572864;        // 65536
    float* X0       = ws + 1638400;        // 65536
    float* X1       = ws + 1703936;        // 65536
    float* mu       = ws + 1769472;        // 16384
    float* counts_f = ws + 1785856;        // 64 (padded 256)
    float* logprior = ws + 1786112;        // 64 (padded 256)
    float* rowsum   = ws + 1786368;        // 256
    float* tvec     = ws + 1786624;        // 64 (padded 256)
    int*   cntp     = (int*)(ws + 1786880);// 32*64 ints

    k1_class_sums<<<256, 256, 0, stream>>>(z, y, Sp, cntp);
    k3_ztz<<<256, 256, 0, stream>>>(z, Zp);  // independent of k1/k2
    k2_finalize<<<64, 256, 0, stream>>>(Sp, cntp, mu, counts_f, logprior);
    k3b_assemble<<<256, 256, 0, stream>>>(Zp, mu, counts_f, A, rowsum);
    k4_init<<<64, 256, 0, stream>>>(rowsum, X0);

    float* xs = X0;
    float* xd = X1;
    for (int i = 0; i < 10; ++i) {
        k5_ns<<<64, 256, 0, stream>>>(A, xs, xd);
        float* tmp = xs; xs = xd; xd = tmp;
    }
    // final precision P lives in xs
    k6_tc<<<64, 256, 0, stream>>>(xs, mu, tvec);
    k7_out<<<256, 256, 0, stream>>>(z, xs, mu, logprior, tvec, out);
}

// Round 2
// 242.756 us; speedup vs baseline: 1.2879x; 1.2879x over previous
//
#include <hip/hip_runtime.h>
#include <math.h>

// B=4096, C=64, D=256, EPS=1e-5
#define BB 4096
#define CC 64
#define DD 256
#define EPSV 1e-5f
#define NORMC 4096.00064f  // B + C*EPS

// ---------------- K1: partial class sums + counts ----------------
// grid 256 = 32 bchunks (128 rows) x 8 colchunks (32 cols), 256 threads
__global__ void k1_class_sums(const float* __restrict__ z, const int* __restrict__ y,
                              float* __restrict__ Sp, int* __restrict__ cntp) {
    int bc = blockIdx.x >> 3;   // 0..31
    int cc = blockIdx.x & 7;    // 0..7
    int b0 = bc * 128;
    int c0 = cc * 32;
    __shared__ float acc[64][33];
    __shared__ int ycache[128];
    __shared__ int cnt[64];
    int t = threadIdx.x;
    for (int i = t; i < 64 * 33; i += 256) ((float*)acc)[i] = 0.f;
    if (t < 64) cnt[t] = 0;
    if (t < 128) ycache[t] = y[b0 + t];
    __syncthreads();
    int rr = t >> 5;       // 0..7
    int col = t & 31;      // 0..31
    for (int step = 0; step < 16; ++step) {
        int r = step * 8 + rr;
        float v = z[(b0 + r) * DD + c0 + col];
        atomicAdd(&acc[ycache[r]][col], v);
    }
    if (cc == 0 && t < 128) atomicAdd(&cnt[ycache[t]], 1);
    __syncthreads();
    for (int i = t; i < 64 * 32; i += 256) {
        int c = i >> 5, cl = i & 31;
        Sp[(bc * 64 + c) * DD + c0 + cl] = acc[c][cl];
    }
    if (cc == 0 && t < 64) cntp[bc * 64 + t] = cnt[t];
}

// ---------------- K2: finalize mu, counts_f, logprior ----------------
__global__ void k2_finalize(const float* __restrict__ Sp, const int* __restrict__ cntp,
                            float* __restrict__ mu, float* __restrict__ counts_f,
                            float* __restrict__ logprior) {
    int c = blockIdx.x;
    int t = threadIdx.x;
    __shared__ float cf;
    __shared__ int csum[32];
    if (t < 32) csum[t] = cntp[t * 64 + c];
    __syncthreads();
    if (t == 0) {
        int n = 0;
        for (int i = 0; i < 32; ++i) n += csum[i];
        float cfv = (float)n + EPSV;
        cf = cfv;
        counts_f[c] = cfv;
        logprior[c] = logf(cfv) - logf(NORMC);
    }
    __syncthreads();
    float s = 0.f;
    for (int i = 0; i < 32; ++i) s += Sp[(i * 64 + c) * DD + t];
    mu[c * DD + t] = s / cf;
}

// ---------------- K3: Z^T Z split-K partials ----------------
// grid 256 = 16 splitK x 16 tiles (4x4 of 64x64), 256 threads
__global__ void k3_ztz(const float* __restrict__ z, float* __restrict__ Zp) {
    int ks = blockIdx.x >> 4;
    int tile = blockIdx.x & 15;
    int ti = tile >> 2, tj = tile & 3;
    __shared__ float Za[32][64];
    __shared__ float Zb[32][64];
    int t = threadIdx.x;
    int b0 = ks * 256;
    float accv[4][4];
#pragma unroll
    for (int i = 0; i < 4; ++i)
#pragma unroll
        for (int j = 0; j < 4; ++j) accv[i][j] = 0.f;
    int i0 = (t & 15) * 4, j0 = (t >> 4) * 4;
    for (int sub = 0; sub < 8; ++sub) {
        int r0 = b0 + sub * 32;
        for (int f = t; f < 512; f += 256) {
            int row = f >> 4, c4 = (f & 15) * 4;
            *(float4*)&Za[row][c4] = *(const float4*)&z[(r0 + row) * DD + ti * 64 + c4];
            *(float4*)&Zb[row][c4] = *(const float4*)&z[(r0 + row) * DD + tj * 64 + c4];
        }
        __syncthreads();
#pragma unroll 8
        for (int kk = 0; kk < 32; ++kk) {
            float4 a = *(float4*)&Za[kk][i0];
            float4 b = *(float4*)&Zb[kk][j0];
            float av[4] = {a.x, a.y, a.z, a.w};
            float bv[4] = {b.x, b.y, b.z, b.w};
#pragma unroll
            for (int ii = 0; ii < 4; ++ii)
#pragma unroll
                for (int jj = 0; jj < 4; ++jj) accv[ii][jj] += av[ii] * bv[jj];
        }
        __syncthreads();
    }
    float* outp = Zp + ks * 65536;
#pragma unroll
    for (int ii = 0; ii < 4; ++ii) {
        int d = ti * 64 + i0 + ii;
        float4 v = make_float4(accv[ii][0], accv[ii][1], accv[ii][2], accv[ii][3]);
        *(float4*)&outp[d * DD + tj * 64 + j0] = v;
    }
}

// ---------------- K3b: assemble A ----------------
__global__ void k3b_assemble(const float* __restrict__ Zp, const float* __restrict__ mu,
                             const float* __restrict__ counts_f,
                             float* __restrict__ A, float* __restrict__ rowsum) {
    int d = blockIdx.x, e = threadIdx.x;
    __shared__ float wmu[64];
    __shared__ float red[4];
    if (e < 64) wmu[e] = (counts_f[e] + EPSV) * mu[e * DD + d];
    __syncthreads();
    float s = 0.f;
    for (int k = 0; k < 16; ++k) s += Zp[k * 65536 + d * DD + e];
    float corr = 0.f;
    for (int c = 0; c < 64; ++c) corr += wmu[c] * mu[c * DD + e];
    float val = (s - corr) * (1.0f / NORMC);
    if (d == e) val += EPSV;
    A[d * DD + e] = val;
    float v = fabsf(val);
    for (int off = 32; off > 0; off >>= 1) v += __shfl_down(v, off, 64);
    if ((e & 63) == 0) red[e >> 6] = v;
    __syncthreads();
    if (e == 0) rowsum[d] = red[0] + red[1] + red[2] + red[3];
}

// ---------------- K4: X0 = (1/max_rowsum) * I ----------------
__global__ void k4_init(const float* __restrict__ rowsum, float* __restrict__ X) {
    __shared__ float red[256];
    int t = threadIdx.x;
    red[t] = rowsum[t];
    __syncthreads();
    for (int off = 128; off > 0; off >>= 1) {
        if (t < off) red[t] = fmaxf(red[t], red[t + off]);
        __syncthreads();
    }
    float alpha = 1.0f / red[0];
    int r0 = blockIdx.x * 4;
#pragma unroll
    for (int r = 0; r < 4; ++r)
        X[(r0 + r) * DD + t] = ((r0 + r) == t) ? alpha : 0.f;
}

// ---------------- K5: Newton-Schulz iteration, 1 row per block ----------------
// grid 256, 256 threads. Xd_row = 2*Xs_row - (Xs_row*A)*Xs
__global__ void k5_ns(const float* __restrict__ A, const float* __restrict__ Xs,
                      float* __restrict__ Xd) {
    int row = blockIdx.x;
    int t = threadIdx.x;
    __shared__ float xl[256];
    __shared__ float rl[256];
    xl[t] = Xs[row * DD + t];
    __syncthreads();
    float acc = 0.f;
#pragma unroll 8
    for (int k = 0; k < 256; ++k) acc += xl[k] * A[k * DD + t];
    rl[t] = acc;
    __syncthreads();
    float o = 2.f * xl[t];
#pragma unroll 8
    for (int k = 0; k < 256; ++k) o -= rl[k] * Xs[k * DD + t];
    Xd[row * DD + t] = o;
}

// ---------------- K6: t_c = mu_c^T P mu_c ----------------
__global__ void k6_tc(const float* __restrict__ P, const float* __restrict__ mu,
                      float* __restrict__ tvec) {
    int c = blockIdx.x, t = threadIdx.x;
    __shared__ float mrow[256];
    __shared__ float red[4];
    mrow[t] = mu[c * DD + t];
    __syncthreads();
    float w = 0.f;
    for (int k = 0; k < 256; ++k) w += mrow[k] * P[k * DD + t];
    float v = w * mrow[t];
    for (int off = 32; off > 0; off >>= 1) v += __shfl_down(v, off, 64);
    if ((t & 63) == 0) red[t >> 6] = v;
    __syncthreads();
    if (t == 0) tvec[c] = red[0] + red[1] + red[2] + red[3];
}

// ---------------- K_zp: ZP = Z * P  (4096x256 @ 256x256), 64x64 tiles ----------------
// grid 256 = 64 rowtiles x 4 coltiles, 256 threads, 4x4 micro-tile
__global__ void k_zp(const float* __restrict__ z, const float* __restrict__ P,
                     float* __restrict__ ZP) {
    __shared__ float Zs[16][68];   // [k][row], padded; 272B row stride -> b128 aligned
    __shared__ float Ps[16][68];   // [k][col]
    int t = threadIdx.x;
    int by = blockIdx.x >> 2, bx = blockIdx.x & 3;
    int r0 = by * 64, c0 = bx * 64;
    int rr = t >> 4, cc = t & 15;
    float acc[4][4];
#pragma unroll
    for (int i = 0; i < 4; ++i)
#pragma unroll
        for (int j = 0; j < 4; ++j) acc[i][j] = 0.f;
    int zrow = t >> 2, zseg = t & 3;
    int pk = t >> 4, pseg = t & 15;
    for (int k0 = 0; k0 < 256; k0 += 16) {
        float4 zv = *(const float4*)&z[(r0 + zrow) * DD + k0 + zseg * 4];
        float4 pv = *(const float4*)&P[(k0 + pk) * DD + c0 + pseg * 4];
        __syncthreads();
        int kb = zseg * 4;
        Zs[kb + 0][zrow] = zv.x;
        Zs[kb + 1][zrow] = zv.y;
        Zs[kb + 2][zrow] = zv.z;
        Zs[kb + 3][zrow] = zv.w;
        *(float4*)&Ps[pk][pseg * 4] = pv;
        __syncthreads();
#pragma unroll
        for (int k = 0; k < 16; ++k) {
            float4 a = *(float4*)&Zs[k][rr * 4];
            float4 b = *(float4*)&Ps[k][cc * 4];
            float av[4] = {a.x, a.y, a.z, a.w};
            float bv[4] = {b.x, b.y, b.z, b.w};
#pragma unroll
            for (int i = 0; i < 4; ++i)
#pragma unroll
                for (int j = 0; j < 4; ++j) acc[i][j] += av[i] * bv[j];
        }
    }
#pragma unroll
    for (int i = 0; i < 4; ++i) {
        float4 v = make_float4(acc[i][0], acc[i][1], acc[i][2], acc[i][3]);
        *(float4*)&ZP[(r0 + rr * 4 + i) * DD + c0 + cc * 4] = v;
    }
}

// ---------------- K_out: out = logprior + ZP*mu^T - 0.5*(q + t_c) ----------------
// grid 256 (16 rows each), 256 threads
__global__ void k_out(const float* __restrict__ z, const float* __restrict__ ZP,
                      const float* __restrict__ mu, const float* __restrict__ logprior,
                      const float* __restrict__ tvec, float* __restrict__ out) {
    __shared__ float muS[256][68];  // [k][c] transposed mu; 272B stride -> aligned
    __shared__ float ZPl[16][260];  // 1040B stride -> aligned
    __shared__ float qs[16];
    __shared__ float lp[64], tc[64];
    int t = threadIdx.x;
    int b0 = blockIdx.x * 16;
    if (t < 64) { lp[t] = logprior[t]; tc[t] = tvec[t]; }
    // stage mu transposed: thread covers class c = t>>2, seg = t&3
    {
        int c = t >> 2, seg = t & 3;
#pragma unroll
        for (int j = 0; j < 16; ++j) {
            int kb = j * 16 + seg * 4;
            float4 v = *(const float4*)&mu[c * DD + kb];
            muS[kb + 0][c] = v.x;
            muS[kb + 1][c] = v.y;
            muS[kb + 2][c] = v.z;
            muS[kb + 3][c] = v.w;
        }
    }
    // stage ZP rows + fused q = sum_k ZP[b][k]*z[b][k]
    {
        int r = t >> 4, base = t & 15;
        float qp = 0.f;
#pragma unroll
        for (int j = 0; j < 4; ++j) {
            int seg = base + 16 * j;  // float4 index 0..63
            float4 v = *(const float4*)&ZP[(b0 + r) * DD + seg * 4];
            float4 zv = *(const float4*)&z[(b0 + r) * DD + seg * 4];
            *(float4*)&ZPl[r][seg * 4] = v;
            qp += v.x * zv.x + v.y * zv.y + v.z * zv.z + v.w * zv.w;
        }
        for (int off = 8; off > 0; off >>= 1) qp += __shfl_down(qp, off, 16);
        if (base == 0) qs[r] = qp;
    }
    __syncthreads();
    int r = t >> 4, cg = t & 15;
    float g0 = 0.f, g1 = 0.f, g2 = 0.f, g3 = 0.f;
#pragma unroll 8
    for (int k = 0; k < 256; ++k) {
        float zp = ZPl[r][k];
        float4 m = *(float4*)&muS[k][cg * 4];
        g0 += zp * m.x; g1 += zp * m.y; g2 += zp * m.z; g3 += zp * m.w;
    }
    float qv = qs[r];
    int c = cg * 4;
    float4 o;
    o.x = lp[c + 0] + g0 - 0.5f * (qv + tc[c + 0]);
    o.y = lp[c + 1] + g1 - 0.5f * (qv + tc[c + 1]);
    o.z = lp[c + 2] + g2 - 0.5f * (qv + tc[c + 2]);
    o.w = lp[c + 3] + g3 - 0.5f * (qv + tc[c + 3]);
    *(float4*)&out[(b0 + r) * CC + c] = o;
}

extern "C" void kernel_launch(void* const* d_in, const int* in_sizes, int n_in,
                              void* d_out, int out_size, void* d_ws, size_t ws_size,
                              hipStream_t stream) {
    const float* z = (const float*)d_in[0];
    const int* y = (const int*)d_in[1];
    float* out = (float*)d_out;
    float* ws = (float*)d_ws;

    // workspace layout (floats)
    float* Sp       = ws;                  // 32*64*256 = 524288 (dead after k2)
    float* ZP       = ws;                  // 4096*256 = 1048576 — ALIASES Sp (k_zp runs after k2)
    float* Zp       = ws + 524288;         // 16*65536  = 1048576 (dead after k3b)
    float* A        = ws + 1572864;        // 65536
    float* X0       = ws + 1638400;        // 65536
    float* X1       = ws + 1703936;        // 65536
    float* mu       = ws + 1769472;        // 16384
    float* counts_f = ws + 1785856;        // 64 (padded 256)
    float* logprior = ws + 1786112;        // 64 (padded 256)
    float* rowsum   = ws + 1786368;        // 256
    float* tvec     = ws + 1786624;        // 64 (padded 256)
    int*   cntp     = (int*)(ws + 1786880);// 32*64 ints

    k1_class_sums<<<256, 256, 0, stream>>>(z, y, Sp, cntp);
    k3_ztz<<<256, 256, 0, stream>>>(z, Zp);
    k2_finalize<<<64, 256, 0, stream>>>(Sp, cntp, mu, counts_f, logprior);
    k3b_assemble<<<256, 256, 0, stream>>>(Zp, mu, counts_f, A, rowsum);
    k4_init<<<64, 256, 0, stream>>>(rowsum, X0);

    float* xs = X0;
    float* xd = X1;
    for (int i = 0; i < 8; ++i) {   // 8 iters: Gershgorin residual^256 ~ 2e-12
        k5_ns<<<256, 256, 0, stream>>>(A, xs, xd);
        float* tmp = xs; xs = xd; xd = tmp;
    }
    // final precision P lives in xs (== X0 after even count)
    k6_tc<<<64, 256, 0, stream>>>(xs, mu, tvec);
    k_zp<<<256, 256, 0, stream>>>(z, xs, ZP);
    k_out<<<256, 256, 0, stream>>>(z, ZP, mu, logprior, tvec, out);
}